// Round 1
// baseline (2770.592 us; speedup 1.0000x reference)
//
#include <hip/hip_runtime.h>
#include <math.h>

#define BSZ 16384
#define MB  19
#define KIN 4864   // M*DIM
#define TR  16     // rows per block in main kernel

// ---------------- Kernel P: fold Wf into Wg's first 128 cols ----------------
// Wc[m][o][d] = sum_k Wg[m][o][k] * Wf[m][k][d]   (k,d < 128, o < 256)
// bc[m][o]    = bg[m][o] + sum_k Wg[m][o][k] * bf[m][k]
__global__ __launch_bounds__(128) void kp_combine(
    const float* __restrict__ Wg, const float* __restrict__ Wf,
    const float* __restrict__ bf, const float* __restrict__ bg,
    float* __restrict__ Wc, float* __restrict__ bc) {
  int mo = blockIdx.x;        // m*256 + o
  int m = mo >> 8;
  int d = threadIdx.x;
  __shared__ float wg_s[128];
  wg_s[d] = Wg[(size_t)mo * 384 + d];
  __syncthreads();
  float acc = 0.f;
  for (int k = 0; k < 128; ++k)
    acc = fmaf(wg_s[k], Wf[(m * 128 + k) * 128 + d], acc);
  Wc[(size_t)mo * 128 + d] = acc;
  if (d == 0) {
    float b = bg[mo];
    for (int k = 0; k < 128; ++k) b = fmaf(wg_s[k], bf[m * 128 + k], b);
    bc[mo] = b;
  }
}

// ---------------- Kernel 1: fea_u = sum_m x3; h_pre = relu(fea_u @ W1^T + b1)
__global__ __launch_bounds__(256) void k1_fc1(
    const float* __restrict__ x, const float* __restrict__ W1,
    const float* __restrict__ b1, float* __restrict__ h_pre) {
  int b = blockIdx.x, t = threadIdx.x;
  __shared__ float fu[256];
  const float* xr = x + (size_t)b * KIN;
  float s = 0.f;
  for (int m = 0; m < MB; ++m) s += xr[m * 256 + t];
  fu[t] = s;
  __syncthreads();
  if (t < 128) {
    float acc = b1[t];
    const float* w = W1 + t * 256;
    for (int j = 0; j < 256; j += 4) {
      float4 wv = *(const float4*)(w + j);
      float4 fv = *(const float4*)(&fu[j]);
      acc = fmaf(wv.x, fv.x, acc); acc = fmaf(wv.y, fv.y, acc);
      acc = fmaf(wv.z, fv.z, acc); acc = fmaf(wv.w, fv.w, acc);
    }
    h_pre[(size_t)b * 128 + t] = fmaxf(acc, 0.f);
  }
}

// ---------------- Kernel 2: per-feature batch sum / sumsq (atomics) --------
__global__ __launch_bounds__(256) void k2_stats(
    const float* __restrict__ h_pre, float* __restrict__ gsum, float* __restrict__ gsq) {
  int t = threadIdx.x;
  int d = t & 127, rh = t >> 7;
  int b0 = blockIdx.x * 64;
  float s = 0.f, q = 0.f;
  for (int r = rh; r < 64; r += 2) {
    float v = h_pre[(size_t)(b0 + r) * 128 + d];
    s += v; q = fmaf(v, v, q);
  }
  __shared__ float ls[256], lq[256];
  ls[t] = s; lq[t] = q;
  __syncthreads();
  if (t < 128) {
    atomicAdd(&gsum[d], ls[t] + ls[t + 128]);
    atomicAdd(&gsq[d],  lq[t] + lq[t + 128]);
  }
}

// ---------------- Kernel 2b: finalize BN scale/shift -----------------------
__global__ __launch_bounds__(128) void k2b_finalize(
    const float* __restrict__ gsum, const float* __restrict__ gsq,
    const float* __restrict__ gamma, const float* __restrict__ beta,
    float* __restrict__ scale, float* __restrict__ shift) {
  int d = threadIdx.x;
  float mu  = gsum[d] * (1.f / BSZ);
  float var = gsq[d]  * (1.f / BSZ) - mu * mu;
  float sc  = gamma[d] * rsqrtf(var + 1e-5f);
  scale[d] = sc;
  shift[d] = fmaf(-mu, sc, beta[d]);
}

// ---------------- Kernel 3: fused fc2 + logits + online softmax + mix ------
__global__ __launch_bounds__(256) void k3_main(
    const float* __restrict__ x, const float* __restrict__ g,
    const float* __restrict__ h_pre, const float* __restrict__ scale,
    const float* __restrict__ shift,
    const float* __restrict__ W2, const float* __restrict__ b2,
    const float* __restrict__ Wc, const float* __restrict__ bc,
    const float* __restrict__ Wg, float* __restrict__ out) {
  __shared__ float h_s[TR][128];
  __shared__ float fz_s[TR][128];
  __shared__ float g_s[TR][256];
  const int b0 = blockIdx.x * TR;
  const int t = threadIdx.x;

  // stage h with BN applied
#pragma unroll
  for (int i = 0; i < (TR * 128) / 256; ++i) {
    int idx = i * 256 + t;
    int r = idx >> 7, d = idx & 127;
    h_s[r][d] = fmaf(h_pre[(size_t)(b0 + r) * 128 + d], scale[d], shift[d]);
  }
  __syncthreads();

  // fea_z = h @ W2^T + b2
  {
    int d = t & 127, rh = t >> 7;
    for (int r = rh; r < TR; r += 2) {
      float acc = b2[d];
      const float* w = W2 + d * 128;
      for (int j = 0; j < 128; j += 4) {
        float4 wv = *(const float4*)(w + j);
        float4 hv = *(const float4*)(&h_s[r][j]);
        acc = fmaf(wv.x, hv.x, acc); acc = fmaf(wv.y, hv.y, acc);
        acc = fmaf(wv.z, hv.z, acc); acc = fmaf(wv.w, hv.w, acc);
      }
      fz_s[r][d] = acc;
    }
  }
  __syncthreads();

  const int o = t;  // 0..255 output column
  float Mx[TR], Sm[TR], Ov[TR];
#pragma unroll
  for (int r = 0; r < TR; ++r) { Mx[r] = -1e30f; Sm[r] = 0.f; Ov[r] = 0.f; }

  for (int m = 0; m < MB; ++m) {
    // stage g tile for this branch
#pragma unroll
    for (int i = 0; i < TR; ++i) {
      int idx = i * 256 + t;
      int r = idx >> 8, k = idx & 255;
      g_s[r][k] = g[(size_t)(b0 + r) * KIN + m * 256 + k];
    }
    __syncthreads();

    float acc[TR];
    {
      float bcv = bc[m * 256 + o];
#pragma unroll
      for (int r = 0; r < TR; ++r) acc[r] = bcv;
    }

    // part 1: Wc[m][o][:] . fea_z[r][:]   (k < 128)
    const float* wr = Wc + ((size_t)m * 256 + o) * 128;
    for (int kc = 0; kc < 128; kc += 16) {
      float4 w0 = *(const float4*)(wr + kc);
      float4 w1 = *(const float4*)(wr + kc + 4);
      float4 w2 = *(const float4*)(wr + kc + 8);
      float4 w3 = *(const float4*)(wr + kc + 12);
#pragma unroll
      for (int r = 0; r < TR; ++r) {
        float4 a0 = *(const float4*)(&fz_s[r][kc]);
        float4 a1 = *(const float4*)(&fz_s[r][kc + 4]);
        float4 a2 = *(const float4*)(&fz_s[r][kc + 8]);
        float4 a3 = *(const float4*)(&fz_s[r][kc + 12]);
        float a = acc[r];
        a = fmaf(w0.x, a0.x, a); a = fmaf(w0.y, a0.y, a); a = fmaf(w0.z, a0.z, a); a = fmaf(w0.w, a0.w, a);
        a = fmaf(w1.x, a1.x, a); a = fmaf(w1.y, a1.y, a); a = fmaf(w1.z, a1.z, a); a = fmaf(w1.w, a1.w, a);
        a = fmaf(w2.x, a2.x, a); a = fmaf(w2.y, a2.y, a); a = fmaf(w2.z, a2.z, a); a = fmaf(w2.w, a2.w, a);
        a = fmaf(w3.x, a3.x, a); a = fmaf(w3.y, a3.y, a); a = fmaf(w3.z, a3.z, a); a = fmaf(w3.w, a3.w, a);
        acc[r] = a;
      }
    }

    // part 2: Wg[m][o][128:384] . g3[r][:]   (k < 256)
    const float* wr2 = Wg + ((size_t)m * 256 + o) * 384 + 128;
    for (int kc = 0; kc < 256; kc += 16) {
      float4 w0 = *(const float4*)(wr2 + kc);
      float4 w1 = *(const float4*)(wr2 + kc + 4);
      float4 w2 = *(const float4*)(wr2 + kc + 8);
      float4 w3 = *(const float4*)(wr2 + kc + 12);
#pragma unroll
      for (int r = 0; r < TR; ++r) {
        float4 a0 = *(const float4*)(&g_s[r][kc]);
        float4 a1 = *(const float4*)(&g_s[r][kc + 4]);
        float4 a2 = *(const float4*)(&g_s[r][kc + 8]);
        float4 a3 = *(const float4*)(&g_s[r][kc + 12]);
        float a = acc[r];
        a = fmaf(w0.x, a0.x, a); a = fmaf(w0.y, a0.y, a); a = fmaf(w0.z, a0.z, a); a = fmaf(w0.w, a0.w, a);
        a = fmaf(w1.x, a1.x, a); a = fmaf(w1.y, a1.y, a); a = fmaf(w1.z, a1.z, a); a = fmaf(w1.w, a1.w, a);
        a = fmaf(w2.x, a2.x, a); a = fmaf(w2.y, a2.y, a); a = fmaf(w2.z, a2.z, a); a = fmaf(w2.w, a2.w, a);
        a = fmaf(w3.x, a3.x, a); a = fmaf(w3.y, a3.y, a); a = fmaf(w3.z, a3.z, a); a = fmaf(w3.w, a3.w, a);
        acc[r] = a;
      }
    }

    // online softmax update + weighted x accumulation
    const float* xp = x + (size_t)b0 * KIN + m * 256 + o;
#pragma unroll
    for (int r = 0; r < TR; ++r) {
      float l = acc[r];
      float xv = xp[(size_t)r * KIN];
      float mn = fmaxf(Mx[r], l);
      float eM = __expf(Mx[r] - mn);
      float el = __expf(l - mn);
      Sm[r] = fmaf(Sm[r], eM, el);
      Ov[r] = fmaf(Ov[r], eM, el * xv);
      Mx[r] = mn;
    }
    __syncthreads();  // before next m overwrites g_s
  }

#pragma unroll
  for (int r = 0; r < TR; ++r)
    out[(size_t)(b0 + r) * 256 + o] = Ov[r] / Sm[r];
}

extern "C" void kernel_launch(void* const* d_in, const int* in_sizes, int n_in,
                              void* d_out, int out_size, void* d_ws, size_t ws_size,
                              hipStream_t stream) {
  const float* x     = (const float*)d_in[0];
  const float* g     = (const float*)d_in[1];
  const float* W1    = (const float*)d_in[2];
  const float* b1    = (const float*)d_in[3];
  const float* gamma = (const float*)d_in[4];
  const float* beta  = (const float*)d_in[5];
  const float* W2    = (const float*)d_in[6];
  const float* b2    = (const float*)d_in[7];
  const float* Wf    = (const float*)d_in[8];
  const float* bf    = (const float*)d_in[9];
  const float* Wg    = (const float*)d_in[10];
  const float* bg    = (const float*)d_in[11];
  float* out = (float*)d_out;

  float* ws    = (float*)d_ws;
  float* h_pre = ws;                                 // 16384*128
  float* Wc    = h_pre + (size_t)BSZ * 128;          // 19*256*128
  float* bc    = Wc + (size_t)MB * 256 * 128;        // 19*256
  float* gsum  = bc + MB * 256;                      // 128
  float* gsq   = gsum + 128;                         // 128
  float* scale = gsq + 128;                          // 128
  float* shift = scale + 128;                        // 128

  hipMemsetAsync(gsum, 0, 256 * sizeof(float), stream);
  kp_combine<<<MB * 256, 128, 0, stream>>>(Wg, Wf, bf, bg, Wc, bc);
  k1_fc1<<<BSZ, 256, 0, stream>>>(x, W1, b1, h_pre);
  k2_stats<<<256, 256, 0, stream>>>(h_pre, gsum, gsq);
  k2b_finalize<<<1, 128, 0, stream>>>(gsum, gsq, gamma, beta, scale, shift);
  k3_main<<<BSZ / TR, 256, 0, stream>>>(x, g, h_pre, scale, shift, W2, b2, Wc, bc, Wg, out);
}

// Round 2
// 1265.386 us; speedup vs baseline: 2.1895x; 2.1895x over previous
//
#include <hip/hip_runtime.h>
#include <math.h>

#define BSZ 16384
#define MB  19
#define KIN 4864   // M*DIM
#define TR3 32     // rows per block in main kernel

typedef __attribute__((ext_vector_type(8))) short short8;
typedef __attribute__((ext_vector_type(4))) float float4v;

static __device__ inline unsigned short f2bf(float f) {
  union { float f; unsigned u; } c; c.f = f;
  unsigned r = c.u + 0x7FFF + ((c.u >> 16) & 1);   // RTNE
  return (unsigned short)(r >> 16);
}

// ---------------- Kernel P: fold Wf into Wg; emit bf16 Wall[m][o][384] ------
// Wall[mo][d]      = bf16( sum_k Wg[mo][k] * Wf[m][k][d] )     d<128
// Wall[mo][128+j]  = bf16( Wg[mo][128+j] )                     j<256
// bc[mo]           = bg[mo] + sum_k Wg[mo][k] * bf[m][k]
__global__ __launch_bounds__(128) void kp_combine(
    const float* __restrict__ Wg, const float* __restrict__ Wf,
    const float* __restrict__ bf, const float* __restrict__ bg,
    unsigned short* __restrict__ Wall, float* __restrict__ bc) {
  int mo = blockIdx.x;        // m*256 + o
  int m = mo >> 8;
  int d = threadIdx.x;
  __shared__ float wg_s[128];
  wg_s[d] = Wg[(size_t)mo * 384 + d];
  __syncthreads();
  float acc = 0.f;
  for (int k = 0; k < 128; ++k)
    acc = fmaf(wg_s[k], Wf[(m * 128 + k) * 128 + d], acc);
  unsigned short* wr = Wall + (size_t)mo * 384;
  wr[d]       = f2bf(acc);
  wr[128 + d] = f2bf(Wg[(size_t)mo * 384 + 128 + d]);
  wr[256 + d] = f2bf(Wg[(size_t)mo * 384 + 256 + d]);
  if (d == 0) {
    float b = bg[mo];
    for (int k = 0; k < 128; ++k) b = fmaf(wg_s[k], bf[m * 128 + k], b);
    bc[mo] = b;
  }
}

// ---------------- Kernel 1: fea_u + fc1 + ReLU, 8 rows/block ---------------
__global__ __launch_bounds__(256) void k1_fc1(
    const float* __restrict__ x, const float* __restrict__ W1,
    const float* __restrict__ b1, float* __restrict__ h_pre) {
  __shared__ float fu[8][256];
  int b0 = blockIdx.x * 8, t = threadIdx.x;
  for (int r = 0; r < 8; ++r) {
    const float* xr = x + (size_t)(b0 + r) * KIN + t;
    float s = 0.f;
    for (int m = 0; m < MB; ++m) s += xr[m * 256];
    fu[r][t] = s;
  }
  __syncthreads();
  int d = t & 127, rr = t >> 7;   // rr: 0..1 (wave-uniform) -> rows rr*4..rr*4+3
  float acc[4];
  float bv = b1[d];
#pragma unroll
  for (int q = 0; q < 4; ++q) acc[q] = bv;
  const float* w = W1 + d * 256;
  for (int j = 0; j < 256; j += 4) {
    float4 wv = *(const float4*)(w + j);
#pragma unroll
    for (int q = 0; q < 4; ++q) {
      float4 fv = *(const float4*)(&fu[rr * 4 + q][j]);
      acc[q] = fmaf(wv.x, fv.x, acc[q]); acc[q] = fmaf(wv.y, fv.y, acc[q]);
      acc[q] = fmaf(wv.z, fv.z, acc[q]); acc[q] = fmaf(wv.w, fv.w, acc[q]);
    }
  }
#pragma unroll
  for (int q = 0; q < 4; ++q)
    h_pre[(size_t)(b0 + rr * 4 + q) * 128 + d] = fmaxf(acc[q], 0.f);
}

// ---------------- Kernel 2: per-feature batch sum / sumsq (atomics) --------
__global__ __launch_bounds__(256) void k2_stats(
    const float* __restrict__ h_pre, float* __restrict__ gsum, float* __restrict__ gsq) {
  int t = threadIdx.x;
  int d = t & 127, rh = t >> 7;
  int b0 = blockIdx.x * 64;
  float s = 0.f, q = 0.f;
  for (int r = rh; r < 64; r += 2) {
    float v = h_pre[(size_t)(b0 + r) * 128 + d];
    s += v; q = fmaf(v, v, q);
  }
  __shared__ float ls[256], lq[256];
  ls[t] = s; lq[t] = q;
  __syncthreads();
  if (t < 128) {
    atomicAdd(&gsum[d], ls[t] + ls[t + 128]);
    atomicAdd(&gsq[d],  lq[t] + lq[t + 128]);
  }
}

// ---------------- Kernel 2b: finalize BN scale/shift -----------------------
__global__ __launch_bounds__(128) void k2b_finalize(
    const float* __restrict__ gsum, const float* __restrict__ gsq,
    const float* __restrict__ gamma, const float* __restrict__ beta,
    float* __restrict__ scale, float* __restrict__ shift) {
  int d = threadIdx.x;
  float mu  = gsum[d] * (1.f / BSZ);
  float var = gsq[d]  * (1.f / BSZ) - mu * mu;
  float sc  = gamma[d] * rsqrtf(var + 1e-5f);
  scale[d] = sc;
  shift[d] = fmaf(-mu, sc, beta[d]);
}

// ---------------- Kernel 3: MFMA logits + max-free softmax + mix ------------
// block = 512 threads = 8 waves; 32 rows (2 row-tiles of 16).
// wave w handles o columns [w*32, w*32+32) = 2 o-tiles of 16.
__global__ __launch_bounds__(512) void k3_mfma(
    const float* __restrict__ x, const float* __restrict__ g,
    const float* __restrict__ h_pre, const float* __restrict__ scale,
    const float* __restrict__ shift,
    const float* __restrict__ W2, const float* __restrict__ b2,
    const unsigned short* __restrict__ Wall, const float* __restrict__ bc,
    float* __restrict__ out) {
  __shared__ float h_s[TR3][128];           // 16 KB
  __shared__ unsigned short A_s[TR3][392];  // bf16; k 0..127 = fea_z, 128..383 = g; +8 pad
  const int t = threadIdx.x;
  const int b0 = blockIdx.x * TR3;
  const int wave = t >> 6, lane = t & 63;
  const int col = lane & 15, quad = lane >> 4;
  const int o0 = wave * 32;

  // ---- stage h with BN applied (4096 floats, 8 per thread) ----
#pragma unroll
  for (int i = 0; i < 8; ++i) {
    int idx = i * 512 + t;
    int r = idx >> 7, d = idx & 127;
    h_s[r][d] = fmaf(h_pre[(size_t)(b0 + r) * 128 + d], scale[d], shift[d]);
  }
  __syncthreads();

  // ---- fc2: fea_z = h @ W2^T + b2 -> bf16 into A_s[.][0:128] ----
#pragma unroll
  for (int i = 0; i < 8; ++i) {
    int idx = i * 512 + t;
    int r = idx >> 7, d = idx & 127;
    float acc = b2[d];
    const float* w = W2 + d * 128;
    for (int j = 0; j < 128; j += 4) {
      float4 wv = *(const float4*)(w + j);
      float4 hv = *(const float4*)(&h_s[r][j]);   // wave-uniform addr: broadcast
      acc = fmaf(wv.x, hv.x, acc); acc = fmaf(wv.y, hv.y, acc);
      acc = fmaf(wv.z, hv.z, acc); acc = fmaf(wv.w, hv.w, acc);
    }
    A_s[r][d] = f2bf(acc);
  }

  float Sm[4][4], Ov[4][4];   // [tile = rt*2+ot][reg]
#pragma unroll
  for (int i = 0; i < 4; ++i)
#pragma unroll
    for (int j = 0; j < 4; ++j) { Sm[i][j] = 0.f; Ov[i][j] = 0.f; }

  for (int m = 0; m < MB; ++m) {
    // ---- stage g -> bf16 A_s[r][128+k] (8192 elems, 16 per thread) ----
#pragma unroll
    for (int i = 0; i < 4; ++i) {
      int idx = i * 2048 + t * 4;
      int r = idx >> 8, k = idx & 255;
      float4 gv = *(const float4*)(g + (size_t)(b0 + r) * KIN + m * 256 + k);
      ushort4 bv;
      bv.x = f2bf(gv.x); bv.y = f2bf(gv.y); bv.z = f2bf(gv.z); bv.w = f2bf(gv.w);
      *(ushort4*)&A_s[r][128 + k] = bv;
    }
    __syncthreads();   // also covers fc2's A_s writes on m==0

    // ---- MFMA: logits[32 x 32] for this wave ----
    float bcv0 = bc[m * 256 + o0 + col];
    float bcv1 = bc[m * 256 + o0 + 16 + col];
    float4v acc[4];
    acc[0] = float4v{bcv0, bcv0, bcv0, bcv0};   // rt0, ot0
    acc[1] = float4v{bcv1, bcv1, bcv1, bcv1};   // rt0, ot1
    acc[2] = float4v{bcv0, bcv0, bcv0, bcv0};   // rt1, ot0
    acc[3] = float4v{bcv1, bcv1, bcv1, bcv1};   // rt1, ot1

    const unsigned short* wb0 = Wall + (size_t)(m * 256 + o0 + col) * 384;
    const unsigned short* wb1 = wb0 + (size_t)16 * 384;
#pragma unroll
    for (int ks = 0; ks < 12; ++ks) {
      int kb = ks * 32 + quad * 8;
      short8 a0 = *(const short8*)&A_s[col][kb];
      short8 a1 = *(const short8*)&A_s[16 + col][kb];
      short8 b0v = *(const short8*)(wb0 + kb);
      short8 b1v = *(const short8*)(wb1 + kb);
      acc[0] = __builtin_amdgcn_mfma_f32_16x16x32_bf16(a0, b0v, acc[0], 0, 0, 0);
      acc[1] = __builtin_amdgcn_mfma_f32_16x16x32_bf16(a0, b1v, acc[1], 0, 0, 0);
      acc[2] = __builtin_amdgcn_mfma_f32_16x16x32_bf16(a1, b0v, acc[2], 0, 0, 0);
      acc[3] = __builtin_amdgcn_mfma_f32_16x16x32_bf16(a1, b1v, acc[3], 0, 0, 0);
    }

    // ---- max-free online softmax + x-weighted accumulation ----
    // D layout: row = quad*4 + reg, col = lane&15  (within each 16x16 tile)
    const float* xb = x + (size_t)b0 * KIN + m * 256 + o0 + col;
#pragma unroll
    for (int rt = 0; rt < 2; ++rt) {
#pragma unroll
      for (int j = 0; j < 4; ++j) {
        const float* xr = xb + (size_t)(rt * 16 + quad * 4 + j) * KIN;
        float e0 = __expf(acc[rt * 2 + 0][j]);
        float e1 = __expf(acc[rt * 2 + 1][j]);
        float x0 = xr[0];
        float x1 = xr[16];
        Sm[rt * 2 + 0][j] += e0;
        Sm[rt * 2 + 1][j] += e1;
        Ov[rt * 2 + 0][j] = fmaf(e0, x0, Ov[rt * 2 + 0][j]);
        Ov[rt * 2 + 1][j] = fmaf(e1, x1, Ov[rt * 2 + 1][j]);
      }
    }
    __syncthreads();   // before next m overwrites A_s g-region
  }

  // ---- write out ----
#pragma unroll
  for (int rt = 0; rt < 2; ++rt) {
#pragma unroll
    for (int j = 0; j < 4; ++j) {
      int row = b0 + rt * 16 + quad * 4 + j;
      out[(size_t)row * 256 + o0 + col]      = Ov[rt * 2 + 0][j] / Sm[rt * 2 + 0][j];
      out[(size_t)row * 256 + o0 + 16 + col] = Ov[rt * 2 + 1][j] / Sm[rt * 2 + 1][j];
    }
  }
}

extern "C" void kernel_launch(void* const* d_in, const int* in_sizes, int n_in,
                              void* d_out, int out_size, void* d_ws, size_t ws_size,
                              hipStream_t stream) {
  const float* x     = (const float*)d_in[0];
  const float* g     = (const float*)d_in[1];
  const float* W1    = (const float*)d_in[2];
  const float* b1    = (const float*)d_in[3];
  const float* gamma = (const float*)d_in[4];
  const float* beta  = (const float*)d_in[5];
  const float* W2    = (const float*)d_in[6];
  const float* b2    = (const float*)d_in[7];
  const float* Wf    = (const float*)d_in[8];
  const float* bf    = (const float*)d_in[9];
  const float* Wg    = (const float*)d_in[10];
  const float* bg    = (const float*)d_in[11];
  float* out = (float*)d_out;

  float* ws    = (float*)d_ws;
  float* h_pre = ws;                                  // 16384*128 f32 = 8 MB
  unsigned short* Wall = (unsigned short*)(h_pre + (size_t)BSZ * 128); // 19*256*384 bf16
  float* bc    = (float*)(Wall + (size_t)MB * 256 * 384);  // 19*256 f32
  float* gsum  = bc + MB * 256;                       // 128
  float* gsq   = gsum + 128;                          // 128
  float* scale = gsq + 128;                           // 128
  float* shift = scale + 128;                         // 128

  hipMemsetAsync(gsum, 0, 256 * sizeof(float), stream);
  kp_combine<<<MB * 256, 128, 0, stream>>>(Wg, Wf, bf, bg, Wall, bc);
  k1_fc1<<<BSZ / 8, 256, 0, stream>>>(x, W1, b1, h_pre);
  k2_stats<<<256, 256, 0, stream>>>(h_pre, gsum, gsq);
  k2b_finalize<<<1, 128, 0, stream>>>(gsum, gsq, gamma, beta, scale, shift);
  k3_mfma<<<BSZ / TR3, 512, 0, stream>>>(x, g, h_pre, scale, shift, W2, b2, Wall, bc, out);
}

// Round 3
// 879.657 us; speedup vs baseline: 3.1496x; 1.4385x over previous
//
#include <hip/hip_runtime.h>
#include <math.h>

#define BSZ 16384
#define MB  19
#define KIN 4864   // M*DIM

typedef __attribute__((ext_vector_type(8))) short short8;
typedef __attribute__((ext_vector_type(4))) float float4v;

static __device__ inline unsigned short f2bf(float f) {
  union { float f; unsigned u; } c; c.f = f;
  unsigned r = c.u + 0x7FFF + ((c.u >> 16) & 1);   // RTNE
  return (unsigned short)(r >> 16);
}

// ---------------- kw: W1 -> bf16 ----------------
__global__ __launch_bounds__(256) void kw_w1b(const float* __restrict__ W1,
                                              unsigned short* __restrict__ W1b) {
  int i = blockIdx.x * 256 + threadIdx.x;   // 128*256 = 32768
  W1b[i] = f2bf(W1[i]);
}

// ---------------- kp: fold Wf into Wg; emit bf16 Wall[m][o][384] + bc ------
__global__ __launch_bounds__(128) void kp_combine(
    const float* __restrict__ Wg, const float* __restrict__ Wf,
    const float* __restrict__ bf, const float* __restrict__ bg,
    unsigned short* __restrict__ Wall, float* __restrict__ bc) {
  int mo = blockIdx.x;        // m*256 + o
  int m = mo >> 8;
  int d = threadIdx.x;
  __shared__ float wg_s[128];
  wg_s[d] = Wg[(size_t)mo * 384 + d];
  __syncthreads();
  float acc = 0.f;
  for (int k = 0; k < 128; ++k)
    acc = fmaf(wg_s[k], Wf[(m * 128 + k) * 128 + d], acc);
  unsigned short* wr = Wall + (size_t)mo * 384;
  wr[d]       = f2bf(acc);
  wr[128 + d] = f2bf(Wg[(size_t)mo * 384 + 128 + d]);
  wr[256 + d] = f2bf(Wg[(size_t)mo * 384 + 256 + d]);
  if (d == 0) {
    float b = bg[mo];
    for (int k = 0; k < 128; ++k) b = fmaf(wg_s[k], bf[m * 128 + k], b);
    bc[mo] = b;
  }
}

// ---------------- k1: fea_u (bf16) + fc1 via MFMA + ReLU + fused stats -----
// 512 thr = 8 waves, 32 rows/block, grid 512.
__global__ __launch_bounds__(512) void k1_mfma(
    const float* __restrict__ x, const unsigned short* __restrict__ W1b,
    const float* __restrict__ b1, float* __restrict__ h_pre,
    float* __restrict__ gsum, float* __restrict__ gsq) {
  __shared__ unsigned short fuB[32][272];   // pitch 272 shorts: optimal b128 reads
  __shared__ float bs[128], bq[128];
  const int t = threadIdx.x, b0 = blockIdx.x * 32;
  const int w = t >> 6, l = t & 63;

  // phase A: fea_u = sum_m x3, to bf16 LDS
#pragma unroll
  for (int i = 0; i < 4; ++i) {
    int r = w * 4 + i;
    const float* xr = x + (size_t)(b0 + r) * KIN + l * 4;
    float4 s = {0.f, 0.f, 0.f, 0.f};
    for (int m = 0; m < MB; ++m) {
      float4 v = *(const float4*)(xr + m * 256);
      s.x += v.x; s.y += v.y; s.z += v.z; s.w += v.w;
    }
    ushort4 u;
    u.x = f2bf(s.x); u.y = f2bf(s.y); u.z = f2bf(s.z); u.w = f2bf(s.w);
    *(ushort4*)&fuB[r][l * 4] = u;
  }
  if (t < 128) { bs[t] = 0.f; bq[t] = 0.f; }
  __syncthreads();

  // phase B: h = relu(fea_u @ W1^T + b1), MFMA; wave w -> d in [16w, 16w+16)
  const int col = l & 15, q = l >> 4;
  const int d = w * 16 + col;
  float bv = b1[d];
  float4v acc0 = {bv, bv, bv, bv}, acc1 = {bv, bv, bv, bv};
#pragma unroll
  for (int ks = 0; ks < 8; ++ks) {
    short8 a0 = *(const short8*)&fuB[col][ks * 32 + q * 8];
    short8 a1 = *(const short8*)&fuB[16 + col][ks * 32 + q * 8];
    short8 b  = *(const short8*)(W1b + d * 256 + ks * 32 + q * 8);
    acc0 = __builtin_amdgcn_mfma_f32_16x16x32_bf16(a0, b, acc0, 0, 0, 0);
    acc1 = __builtin_amdgcn_mfma_f32_16x16x32_bf16(a1, b, acc1, 0, 0, 0);
  }
  float s = 0.f, qq = 0.f;
#pragma unroll
  for (int j = 0; j < 4; ++j) {
    float v0 = fmaxf(acc0[j], 0.f);
    float v1 = fmaxf(acc1[j], 0.f);
    h_pre[(size_t)(b0 + q * 4 + j) * 128 + d]      = v0;
    h_pre[(size_t)(b0 + 16 + q * 4 + j) * 128 + d] = v1;
    s += v0 + v1; qq = fmaf(v0, v0, qq); qq = fmaf(v1, v1, qq);
  }
  atomicAdd(&bs[d], s);
  atomicAdd(&bq[d], qq);
  __syncthreads();
  if (t < 128) { atomicAdd(&gsum[t], bs[t]); atomicAdd(&gsq[t], bq[t]); }
}

// ---------------- k2b: BN -> fold into W2 (bf16 W2s, f32 b2s) --------------
__global__ __launch_bounds__(128) void k2b_finalize(
    const float* __restrict__ gsum, const float* __restrict__ gsq,
    const float* __restrict__ gamma, const float* __restrict__ beta,
    const float* __restrict__ W2, const float* __restrict__ b2,
    unsigned short* __restrict__ W2s, float* __restrict__ b2s) {
  __shared__ float sc[128], sh[128];
  int d = threadIdx.x;
  float mu  = gsum[d] * (1.f / BSZ);
  float var = gsq[d]  * (1.f / BSZ) - mu * mu;
  float s   = gamma[d] * rsqrtf(var + 1e-5f);
  sc[d] = s;
  sh[d] = beta[d] - mu * s;
  __syncthreads();
  float acc = b2[d];
  for (int k = 0; k < 128; ++k) {
    float w2 = W2[d * 128 + k];
    W2s[d * 128 + k] = f2bf(w2 * sc[k]);
    acc = fmaf(w2, sh[k], acc);
  }
  b2s[d] = acc;
}

// ---------------- k3: fc2-MFMA + logits-MFMA + softmax-mix, fused ----------
// 512 thr = 8 waves, 32 rows/block, grid 512. Double-buffered g staging,
// att transposed through LDS for coalesced x mixing. 2 blocks/CU target.
__global__ __launch_bounds__(512, 4) void k3_fused(
    const float* __restrict__ x, const float* __restrict__ g,
    const float* __restrict__ h_pre,
    const unsigned short* __restrict__ W2s, const float* __restrict__ b2s,
    const unsigned short* __restrict__ Wall, const float* __restrict__ bc,
    float* __restrict__ out) {
  __shared__ unsigned short fz[32][144];        // 9.2 KB  (pitch 144: optimal b128)
  __shared__ unsigned short gb[2][32][272];     // 34.8 KB (pitch 272: optimal b128)
  __shared__ float att[32][260];                // 33.3 KB (pitch 260: optimal b128)
  const int t = threadIdx.x, b0 = blockIdx.x * 32;
  const int w = t >> 6, l = t & 63;
  const int col = l & 15, q = l >> 4;

  // ---- phase 0a: fc2 via MFMA; wave w -> d in [16w, 16w+16) ----
  {
    const int d = w * 16 + col;
    float bv = b2s[d];
    float4v a2_0 = {bv, bv, bv, bv}, a2_1 = {bv, bv, bv, bv};
#pragma unroll
    for (int ks = 0; ks < 4; ++ks) {
      const float* h0 = h_pre + (size_t)(b0 + col) * 128 + ks * 32 + q * 8;
      const float* h1 = h_pre + (size_t)(b0 + 16 + col) * 128 + ks * 32 + q * 8;
      float4 h0a = *(const float4*)h0,  h0b = *(const float4*)(h0 + 4);
      float4 h1a = *(const float4*)h1,  h1b = *(const float4*)(h1 + 4);
      short8 A0, A1;
      A0[0]=(short)f2bf(h0a.x); A0[1]=(short)f2bf(h0a.y); A0[2]=(short)f2bf(h0a.z); A0[3]=(short)f2bf(h0a.w);
      A0[4]=(short)f2bf(h0b.x); A0[5]=(short)f2bf(h0b.y); A0[6]=(short)f2bf(h0b.z); A0[7]=(short)f2bf(h0b.w);
      A1[0]=(short)f2bf(h1a.x); A1[1]=(short)f2bf(h1a.y); A1[2]=(short)f2bf(h1a.z); A1[3]=(short)f2bf(h1a.w);
      A1[4]=(short)f2bf(h1b.x); A1[5]=(short)f2bf(h1b.y); A1[6]=(short)f2bf(h1b.z); A1[7]=(short)f2bf(h1b.w);
      short8 B = *(const short8*)(W2s + d * 128 + ks * 32 + q * 8);
      a2_0 = __builtin_amdgcn_mfma_f32_16x16x32_bf16(A0, B, a2_0, 0, 0, 0);
      a2_1 = __builtin_amdgcn_mfma_f32_16x16x32_bf16(A1, B, a2_1, 0, 0, 0);
    }
#pragma unroll
    for (int j = 0; j < 4; ++j) {
      fz[q * 4 + j][d]      = f2bf(a2_0[j]);
      fz[16 + q * 4 + j][d] = f2bf(a2_1[j]);
    }
  }
  // ---- phase 0b: stage g(m=0) -> gb[0] ----
#pragma unroll
  for (int i = 0; i < 4; ++i) {
    int r = i * 8 + w;
    float4 gv = *(const float4*)(g + (size_t)(b0 + r) * KIN + l * 4);
    ushort4 u;
    u.x = f2bf(gv.x); u.y = f2bf(gv.y); u.z = f2bf(gv.z); u.w = f2bf(gv.w);
    *(ushort4*)&gb[0][r][l * 4] = u;
  }
  __syncthreads();

  float4v Ov[4], Sm[4];
#pragma unroll
  for (int u = 0; u < 4; ++u) { Ov[u] = float4v{0,0,0,0}; Sm[u] = float4v{0,0,0,0}; }

  const int o0 = w * 32;
  const int mr = t >> 4, mc = t & 15;   // mix-phase ownership: row mr, cols 4*mc + 64u

  for (int m = 0; m < MB; ++m) {
    const int p = m & 1;
    // ---- logits MFMA: wave tile 32 rows x 32 cols ----
    float bc0 = bc[m * 256 + o0 + col];
    float bc1 = bc[m * 256 + o0 + 16 + col];
    float4v acc[4];
    acc[0] = float4v{bc0, bc0, bc0, bc0};
    acc[1] = float4v{bc1, bc1, bc1, bc1};
    acc[2] = float4v{bc0, bc0, bc0, bc0};
    acc[3] = float4v{bc1, bc1, bc1, bc1};
    const unsigned short* wb0 = Wall + (size_t)(m * 256 + o0 + col) * 384;
    const unsigned short* wb1 = wb0 + (size_t)16 * 384;
#pragma unroll
    for (int ks = 0; ks < 12; ++ks) {
      short8 a0, a1;
      if (ks < 4) {
        a0 = *(const short8*)&fz[col][ks * 32 + q * 8];
        a1 = *(const short8*)&fz[16 + col][ks * 32 + q * 8];
      } else {
        a0 = *(const short8*)&gb[p][col][(ks - 4) * 32 + q * 8];
        a1 = *(const short8*)&gb[p][16 + col][(ks - 4) * 32 + q * 8];
      }
      short8 b0v = *(const short8*)(wb0 + ks * 32 + q * 8);
      short8 b1v = *(const short8*)(wb1 + ks * 32 + q * 8);
      acc[0] = __builtin_amdgcn_mfma_f32_16x16x32_bf16(a0, b0v, acc[0], 0, 0, 0);
      acc[1] = __builtin_amdgcn_mfma_f32_16x16x32_bf16(a0, b1v, acc[1], 0, 0, 0);
      acc[2] = __builtin_amdgcn_mfma_f32_16x16x32_bf16(a1, b0v, acc[2], 0, 0, 0);
      acc[3] = __builtin_amdgcn_mfma_f32_16x16x32_bf16(a1, b1v, acc[3], 0, 0, 0);
    }
    // exp -> att_s (transpose through LDS; writes are 2-way = free)
#pragma unroll
    for (int rt = 0; rt < 2; ++rt) {
#pragma unroll
      for (int j = 0; j < 4; ++j) {
        int row = rt * 16 + q * 4 + j;
        att[row][o0 + col]      = __expf(acc[rt * 2 + 0][j]);
        att[row][o0 + 16 + col] = __expf(acc[rt * 2 + 1][j]);
      }
    }
    __syncthreads();

    // ---- mix phase: coalesced x + att from LDS; plus stage g(m+1) ----
    {
      const float* xr = x + (size_t)(b0 + mr) * KIN + m * 256 + mc * 4;
#pragma unroll
      for (int u = 0; u < 4; ++u) {
        float4 xv = *(const float4*)(xr + u * 64);
        float4 ev = *(const float4*)&att[mr][mc * 4 + u * 64];
        Sm[u][0] += ev.x; Sm[u][1] += ev.y; Sm[u][2] += ev.z; Sm[u][3] += ev.w;
        Ov[u][0] = fmaf(ev.x, xv.x, Ov[u][0]);
        Ov[u][1] = fmaf(ev.y, xv.y, Ov[u][1]);
        Ov[u][2] = fmaf(ev.z, xv.z, Ov[u][2]);
        Ov[u][3] = fmaf(ev.w, xv.w, Ov[u][3]);
      }
    }
    if (m + 1 < MB) {
#pragma unroll
      for (int i = 0; i < 4; ++i) {
        int r = i * 8 + w;
        float4 gv = *(const float4*)(g + (size_t)(b0 + r) * KIN + (m + 1) * 256 + l * 4);
        ushort4 u;
        u.x = f2bf(gv.x); u.y = f2bf(gv.y); u.z = f2bf(gv.z); u.w = f2bf(gv.w);
        *(ushort4*)&gb[1 - p][r][l * 4] = u;
      }
    }
    __syncthreads();
  }

  // ---- epilogue ----
#pragma unroll
  for (int u = 0; u < 4; ++u) {
    float4 o4;
    o4.x = Ov[u][0] / Sm[u][0];
    o4.y = Ov[u][1] / Sm[u][1];
    o4.z = Ov[u][2] / Sm[u][2];
    o4.w = Ov[u][3] / Sm[u][3];
    *(float4*)(out + (size_t)(b0 + mr) * 256 + mc * 4 + u * 64) = o4;
  }
}

extern "C" void kernel_launch(void* const* d_in, const int* in_sizes, int n_in,
                              void* d_out, int out_size, void* d_ws, size_t ws_size,
                              hipStream_t stream) {
  const float* x     = (const float*)d_in[0];
  const float* g     = (const float*)d_in[1];
  const float* W1    = (const float*)d_in[2];
  const float* b1    = (const float*)d_in[3];
  const float* gamma = (const float*)d_in[4];
  const float* beta  = (const float*)d_in[5];
  const float* W2    = (const float*)d_in[6];
  const float* b2    = (const float*)d_in[7];
  const float* Wf    = (const float*)d_in[8];
  const float* bf    = (const float*)d_in[9];
  const float* Wg    = (const float*)d_in[10];
  const float* bg    = (const float*)d_in[11];
  float* out = (float*)d_out;

  float* ws = (float*)d_ws;
  float* gsum = ws;                                   // 128
  float* gsq  = gsum + 128;                           // 128
  float* bc   = gsq + 128;                            // 19*256 = 4864
  float* b2s  = bc + MB * 256;                        // 128
  float* h_pre = b2s + 128;                           // 16384*128
  unsigned short* Wall = (unsigned short*)(h_pre + (size_t)BSZ * 128); // 19*256*384
  unsigned short* W1b  = Wall + (size_t)MB * 256 * 384;                // 128*256
  unsigned short* W2s  = W1b + 128 * 256;                              // 128*128

  hipMemsetAsync(gsum, 0, 256 * sizeof(float), stream);
  kw_w1b<<<128, 256, 0, stream>>>(W1, W1b);
  kp_combine<<<MB * 256, 128, 0, stream>>>(Wg, Wf, bf, bg, Wall, bc);
  k1_mfma<<<BSZ / 32, 512, 0, stream>>>(x, W1b, b1, h_pre, gsum, gsq);
  k2b_finalize<<<1, 128, 0, stream>>>(gsum, gsq, gamma, beta, W2, b2, W2s, b2s);
  k3_fused<<<BSZ / 32, 512, 0, stream>>>(x, g, h_pre, W2s, b2s, Wall, bc, out);
}